// Round 8
// baseline (334.799 us; speedup 1.0000x reference)
//
#include <hip/hip_runtime.h>
#include <hip/hip_bf16.h>
#include <hip/hip_cooperative_groups.h>

namespace cg = cooperative_groups;

#define SEQ   512
#define BATCH 256
#define ZD    64

__device__ __forceinline__ float lane_bcastf(float v, int i) {
  return __int_as_float(__builtin_amdgcn_readlane(__float_as_int(v), i));
}
__device__ __forceinline__ int lane_bcasti(int v, int i) {
  return __builtin_amdgcn_readlane(v, i);
}

// 64 distinct scalar names t00..t77 (two octal digits). The literal 0##n is
// an OCTAL constant equal to the linear index: t45 <-> 045 = 4*8+5 = 37.
#define REP8(M,p)  M(p##0) M(p##1) M(p##2) M(p##3) M(p##4) M(p##5) M(p##6) M(p##7)
#define REP64(M)   REP8(M,0) REP8(M,1) REP8(M,2) REP8(M,3) \
                   REP8(M,4) REP8(M,5) REP8(M,6) REP8(M,7)

#define TDECL(n)  float t##n;
#define TLOADF(n) t##n = Trp[0##n];          // T[lane][i], i = 0##n
#define TLOADB(n) t##n = Tcp[(0##n) * ZD];   // T[j][lane], j = 0##n
// Accumulate into 4 chains (constant index -> SROA keeps acc in registers).
#define TFMA(n)   acc[(0##n) & 3] = fmaf(lane_bcastf(vbc, 0##n), t##n, acc[(0##n) & 3]);
// Opaque register pin: stops LICM from re-sinking the T loads into the loop.
#define TPIN(p)   asm volatile("" : "+v"(t##p##0), "+v"(t##p##1), "+v"(t##p##2), \
                                    "+v"(t##p##3), "+v"(t##p##4), "+v"(t##p##5), \
                                    "+v"(t##p##6), "+v"(t##p##7));
#define TPIN_ALL  TPIN(0) TPIN(1) TPIN(2) TPIN(3) TPIN(4) TPIN(5) TPIN(6) TPIN(7)

// Fused HMM forward-backward + posterior, ONE cooperative dispatch.
//
// Phase 1 (chains): the proven 133us structure, unchanged. One wave (64
// lanes = 64 z-states) per chain; blocks 0..255 forward, 256..511 backward.
// Per-step cost model (established R0-R7): ~145 instrs * 4 cyc single-wave
// issue cadence = ~620 cyc/step. All latency/ordering/SGPR experiments were
// flat; only instruction count matters. Left unchanged this round.
//
// Phase 2 (posterior): grid-stride over the same 512x64 threads after a
// grid-wide sync. Fusing removes one dispatch + inter-dispatch gap, which
// accounted for ~80 us of the 240 us total (chains 133 + posterior ~25).
__global__ __launch_bounds__(64, 1) void hmm_fused(
    const int*   __restrict__ inp,    // [SEQ, BATCH]
    const float* __restrict__ T,      // [ZD, ZD] row-major
    const float* __restrict__ pi,     // [ZD]
    const float* __restrict__ emit,   // [X, ZD]
    float* __restrict__ out_alpha,    // [SEQ, BATCH, ZD] fp32
    float* __restrict__ out_beta,     // [SEQ, BATCH, ZD] fp32
    float* __restrict__ out_post)     // [SEQ, BATCH, ZD] fp32
{
  const int lane = threadIdx.x;
  const int blk  = blockIdx.x;
  const bool fwd = (blk < BATCH);
  const int b    = fwd ? blk : blk - BATCH;

  // Whole x-sequence in 8 lane-indexed VGPRs: xv[w] lane l = x[64w + l].
  // In-loop access is a single v_readlane (uniform SGPR) -> zero per-step loads.
  int xv[8];
  #pragma unroll
  for (int w = 0; w < 8; ++w)
    xv[w] = inp[(w * 64 + lane) * BATCH + b];

  REP64(TDECL)

  if (fwd) {
    // alpha_t[l] = e_t[l] * sum_i alpha_{t-1}[i] * T[l][i]
    const float* Trp = T + lane * ZD;
    REP64(TLOADF)
    TPIN_ALL

    const int x0 = lane_bcasti(xv[0], 0);
    float alpha = emit[x0 * ZD + lane] * pi[lane];
    float* op = out_alpha + (size_t)b * ZD + lane;
    *op = alpha;
    op += BATCH * ZD;

    #pragma unroll
    for (int w = 0; w < 8; ++w) {
      const int xvw = xv[w];
      #pragma unroll 1                 // keep body (~1.2 KB) inside L1I
      for (int idx = (w == 0) ? 1 : 0; idx < 64; ++idx) {
        const int   xt = lane_bcasti(xvw, idx);   // x_t (uniform)
        const float e  = emit[xt * ZD + lane];    // issued here, used ~260cyc later
        float acc[4] = {0.f, 0.f, 0.f, 0.f};
        const float vbc = alpha;
        REP64(TFMA)                               // 64 readlane + 64 fma
        alpha = e * ((acc[0] + acc[1]) + (acc[2] + acc[3]));
        *op = alpha;
        op += BATCH * ZD;
      }
    }
  } else {
    // beta_t[l] = sum_j (e_{t+1}[j]*beta_{t+1}[j]) * T[j][l]
    const float* Tcp = T + lane;
    REP64(TLOADB)
    TPIN_ALL

    float beta = 1.0f;
    float* op = out_beta + ((size_t)(SEQ - 1) * BATCH + b) * ZD + lane;
    *op = beta;
    op -= BATCH * ZD;

    const int xL = lane_bcasti(xv[7], 63);
    float e_next = emit[xL * ZD + lane];          // e_{511}, consumed at t=510

    #pragma unroll
    for (int w = 7; w >= 0; --w) {
      const int xvw = xv[w];
      #pragma unroll 1
      for (int idx = (w == 7) ? 62 : 63; idx >= 0; --idx) {
        const int   xt   = lane_bcasti(xvw, idx); // x_t, e for next iteration
        const float e_pf = emit[xt * ZD + lane];
        const float vbc  = e_next * beta;         // g[j] broadcast source
        float acc[4] = {0.f, 0.f, 0.f, 0.f};
        REP64(TFMA)
        beta = (acc[0] + acc[1]) + (acc[2] + acc[3]);
        *op = beta;
        op -= BATCH * ZD;
        e_next = e_pf;
      }
    }
  }

  // All alpha/beta stores must be visible device-wide before the posterior
  // phase reads them (cross-XCD): grid.sync() = device fence + grid barrier.
  cg::this_grid().sync();

  // Phase 2: posterior[t,b,z] = alpha*beta / sum_z(alpha*beta).
  // 8 z per lane (2x float4), 8 lanes per (t,b) row, xor-shuffle reduction
  // within the 8-lane group. Grid-stride: 32768 threads, 1048576 slots.
  const int gtid = blk * 64 + lane;
  #pragma unroll 1
  for (int it = 0; it < (SEQ * BATCH * ZD / 8) / (2 * BATCH * 64); ++it) {
    const size_t slot = (size_t)it * (2 * BATCH * 64) + gtid;
    const size_t base = slot * 8;

    const float4 va0 = *reinterpret_cast<const float4*>(out_alpha + base);
    const float4 va1 = *reinterpret_cast<const float4*>(out_alpha + base + 4);
    const float4 vb0 = *reinterpret_cast<const float4*>(out_beta  + base);
    const float4 vb1 = *reinterpret_cast<const float4*>(out_beta  + base + 4);

    const float p0 = va0.x * vb0.x;
    const float p1 = va0.y * vb0.y;
    const float p2 = va0.z * vb0.z;
    const float p3 = va0.w * vb0.w;
    const float p4 = va1.x * vb1.x;
    const float p5 = va1.y * vb1.y;
    const float p6 = va1.z * vb1.z;
    const float p7 = va1.w * vb1.w;

    float s = ((p0 + p1) + (p2 + p3)) + ((p4 + p5) + (p6 + p7));
    s += __shfl_xor(s, 1);
    s += __shfl_xor(s, 2);
    s += __shfl_xor(s, 4);
    const float inv = 1.0f / s;

    float4 o0, o1;
    o0.x = p0 * inv; o0.y = p1 * inv; o0.z = p2 * inv; o0.w = p3 * inv;
    o1.x = p4 * inv; o1.y = p5 * inv; o1.z = p6 * inv; o1.w = p7 * inv;
    *reinterpret_cast<float4*>(out_post + base)     = o0;
    *reinterpret_cast<float4*>(out_post + base + 4) = o1;
  }
}

extern "C" void kernel_launch(void* const* d_in, const int* in_sizes, int n_in,
                              void* d_out, int out_size, void* d_ws, size_t ws_size,
                              hipStream_t stream) {
  const int*   inp  = (const int*)  d_in[0];
  const float* T    = (const float*)d_in[1];
  const float* pi   = (const float*)d_in[2];
  const float* emit = (const float*)d_in[3];

  float* out = (float*)d_out;
  const size_t N = (size_t)SEQ * BATCH * ZD;   // 8388608 per output
  float* out_alpha = out;
  float* out_beta  = out + N;
  float* out_post  = out + 2 * N;

  void* args[] = {(void*)&inp, (void*)&T, (void*)&pi, (void*)&emit,
                  (void*)&out_alpha, (void*)&out_beta, (void*)&out_post};
  hipLaunchCooperativeKernel(reinterpret_cast<const void*>(hmm_fused),
                             dim3(2 * BATCH), dim3(64), args, 0, stream);
}